// Round 12
// baseline (2861.529 us; speedup 1.0000x reference)
//
#include <hip/hip_runtime.h>

// PN_Critic: conv1d(k=1) -> 512-step LSTM -> time-sum -> fc1(relu) -> fc2
// B=256 S=512 D=128 H1=256 H2=512, gates=2048, combined K = 128+512 = 640.
//
// Round-12: round-11 two-stream kernel UNCHANGED; launch switched from
// hipLaunchCooperativeKernel (silently rejected at grid=128/40KB-LDS ->
// stub-like absmax 22.36 = lstm never ran) to a regular launch. The kernel
// has used no grid.sync since round 7; cooperative launch only provided
// co-residency, which 128 WGs on 256 CUs gets trivially from the dispatcher.
//
// Two-stream design (round-10 theory): round-9 counters showed 3.2us/step,
// MfmaUtil 8.5% -> serial chain store-h -> ack -> flag -> poll -> load is ~4
// coherence-point round trips (~900cyc each, sc0/sc1 bypasses caches).
// B=256 = two independent 128-batch recurrences; 128 WGs each own 16 batches
// of stream A AND 16 of stream B (same gate-cols, SHARED weight registers).
// Schedule A-compute / B-stage / B-compute / A-stage: each stream's exchange
// latency hides under the other stream's GEMM+cell.

typedef __attribute__((ext_vector_type(8))) short s16x8;
typedef __attribute__((ext_vector_type(4))) float f32x4;
typedef __attribute__((ext_vector_type(2))) float f32x2;

#define B_   256
#define S_   512
#define D_   128
#define H1_  256
#define H2_  512
#define G4_  2048
#define K_   640

__device__ __forceinline__ unsigned short f2bf(float f) {
  union { float f; unsigned u; } v; v.f = f;
  unsigned r = v.u + 0x7FFFu + ((v.u >> 16) & 1u);   // round-nearest-even
  return (unsigned short)(r >> 16);
}
__device__ __forceinline__ float sigm(float x) { return 1.f / (1.f + __expf(-x)); }
__device__ __forceinline__ float tanh_(float x) { return 1.f - 2.f / (__expf(2.f * x) + 1.f); }

// ---- device-coherent (cross-XCD, fence-free) memory ops: sc0|sc1 ----------
__device__ __forceinline__ s16x8 ld_cohx8(const unsigned short* p) {
  s16x8 d;
  asm volatile("global_load_dwordx4 %0, %1, off sc0 sc1" : "=v"(d) : "v"(p));
  return d;
}
__device__ __forceinline__ void st_coh_u32(unsigned* p, unsigned v) {
  asm volatile("global_store_dword %0, %1, off sc0 sc1" :: "v"(p), "v"(v) : "memory");
}
__device__ __forceinline__ unsigned ld_coh_u32(const unsigned* p) {
  unsigned d;
  asm volatile("global_load_dword %0, %1, off sc0 sc1\n\ts_waitcnt vmcnt(0)"
               : "=v"(d) : "v"(p) : "memory");
  return d;
}
__device__ __forceinline__ void vm_drain() {
  asm volatile("s_waitcnt vmcnt(0)" ::: "memory");
  __builtin_amdgcn_sched_barrier(0);
}

// ---------------- prep: combined weight + bias, permuted-interleaved rows ---
// storage row np = 32c + 16blk + 4q + g  <->  original n = g*512 + j,
// j = 8c + 2q + blk.  bias kept canonical: bias[4j+g].
__global__ void prep_kernel(const float* __restrict__ conv_w, const float* __restrict__ conv_b,
                            const float* __restrict__ w_ih,   const float* __restrict__ b_ih,
                            const float* __restrict__ w_hh,   const float* __restrict__ b_hh,
                            unsigned short* __restrict__ Wc,  float* __restrict__ bias,
                            unsigned* __restrict__ flags) {
  const int np = blockIdx.x;          // storage row
  const int c = np >> 5, r5 = np & 31;
  const int blk = r5 >> 4, q = (r5 >> 2) & 3, g = r5 & 3;
  const int j = c * 8 + 2 * q + blk;
  const int n = g * H2_ + j;          // original gate row
  const int tid = threadIdx.x;        // 128 threads

  if (np == 0) { flags[tid] = 0; flags[tid + 128] = 0; }  // zero 256 flags (A:0..127 B:128..255)

  __shared__ float wrow[H1_];
  __shared__ float red[128];
  wrow[tid]       = w_ih[(size_t)n * H1_ + tid];
  wrow[tid + 128] = w_ih[(size_t)n * H1_ + tid + 128];
  __syncthreads();

  // x-projection part: k = tid (0..127)
  float acc = 0.f;
  for (int h1 = 0; h1 < H1_; ++h1)
    acc += wrow[h1] * conv_w[(size_t)h1 * D_ + tid];
  Wc[(size_t)np * K_ + tid] = f2bf(acc);

  // recurrent part: copy w_hh row (bf16)
  #pragma unroll
  for (int r = 0; r < 4; ++r)
    Wc[(size_t)np * K_ + 128 + tid + r * 128] = f2bf(w_hh[(size_t)n * H2_ + tid + r * 128]);

  // bias[4j+g] = b_ih + b_hh + w_ih@conv_b
  float p = wrow[tid] * conv_b[tid] + wrow[tid + 128] * conv_b[tid + 128];
  red[tid] = p;
  __syncthreads();
  for (int s = 64; s > 0; s >>= 1) {
    if (tid < s) red[tid] += red[tid + s];
    __syncthreads();
  }
  if (tid == 0) bias[4 * j + g] = red[0] + b_ih[n] + b_hh[n];
}

// ---------------- persistent LSTM: two-stream pipelined ---------------------
__global__ __launch_bounds__(256, 1) void lstm_kernel(
    const float* __restrict__ x, const float* __restrict__ h0,
    const float* __restrict__ c0, const unsigned short* __restrict__ Wc,
    const float* __restrict__ bias, unsigned short* __restrict__ h_bf,
    float* __restrict__ pooled, unsigned* __restrict__ flags) {
  const int wg = blockIdx.x;       // 128 WGs = 8 mg x 16 ng
  const int mg = wg & 7;           // batch-group: A rows mg*16.., B rows 128+mg*16..
  const int ng = wg >> 3;          // gate cols ng*128 .. +128
  const int tid = threadIdx.x;
  const int wv = tid >> 6;         // wave 0..3
  const int lane = tid & 63;

  __shared__ unsigned short Alds[2][16 * K_];   // [stream][row*640], XOR-swizzled

  // --- Wc fragments (A-operand of swapped MFMA), shared by both streams ---
  const int n0 = ng * 128 + wv * 32;
  s16x8 bfrag0[20], bfrag1[20];
  {
    const int bn0 = n0 + (lane & 15);
    const int bk = (lane >> 4) * 8;
    #pragma unroll
    for (int kk = 0; kk < 20; ++kk) {
      bfrag0[kk] = *(const s16x8*)(Wc + (size_t)bn0 * K_ + kk * 32 + bk);
      bfrag1[kk] = *(const s16x8*)(Wc + (size_t)(bn0 + 16) * K_ + kk * 32 + bk);
    }
  }
  #pragma unroll
  for (int kk = 0; kk < 20; ++kk)
    asm volatile("" : "+v"(bfrag0[kk]), "+v"(bfrag1[kk]));

  // --- ownership (adjacent j0,j0+1 via permuted Wc rows) ---
  const int b_ownA = mg * 16 + (lane & 15);
  const int b_ownB = 128 + mg * 16 + (lane & 15);
  const int j0 = ng * 32 + wv * 8 + 2 * (lane >> 4);   // even
  const f32x4 brg0 = *(const f32x4*)(bias + 4 * j0);
  const f32x4 brg1 = *(const f32x4*)(bias + 4 * (j0 + 1));
  f32x2 cA = *(const f32x2*)(c0 + (size_t)b_ownA * H2_ + j0);
  f32x2 cB = *(const f32x2*)(c0 + (size_t)b_ownB * H2_ + j0);
  f32x2 poolA = {0.f, 0.f}, poolB = {0.f, 0.f};

  // staging geometry: 16 rows x 16 col-threads
  const int sr = tid >> 4, sct = tid & 15;
  const int b_stA = mg * 16 + sr;
  const int b_stB = 128 + mg * 16 + sr;
  const unsigned row_base = sr * (K_ * 2);
  const unsigned swz = (unsigned)((sr & 7) << 4);
  const unsigned swz_x = (row_base + sct * 16) ^ swz;

  const int ar = lane & 15;                  // A-tile row for GEMM read
  const int ahi = lane >> 4;                 // k-slice selector
  unsigned* fA = flags + mg * 16;            // stream-A group flags
  unsigned* fB = flags + 128 + mg * 16;      // stream-B group flags

  // ---- prologue: stage x_0 and h_0 for BOTH streams ----
  #pragma unroll
  for (int s = 0; s < 2; ++s) {
    const int b_st = s ? b_stB : b_stA;
    char* lds = (char*)Alds[s];
    {
      const float* xp = x + ((size_t)b_st * S_) * D_ + sct * 8;
      f32x4 v0 = *(const f32x4*)xp;
      f32x4 v1 = *(const f32x4*)(xp + 4);
      s16x8 pk;
      pk[0] = (short)f2bf(v0[0]); pk[1] = (short)f2bf(v0[1]);
      pk[2] = (short)f2bf(v0[2]); pk[3] = (short)f2bf(v0[3]);
      pk[4] = (short)f2bf(v1[0]); pk[5] = (short)f2bf(v1[1]);
      pk[6] = (short)f2bf(v1[2]); pk[7] = (short)f2bf(v1[3]);
      *(s16x8*)(lds + swz_x) = pk;
    }
    const float* hp = h0 + (size_t)b_st * H2_ + sct * 32;
    #pragma unroll
    for (int q = 0; q < 4; ++q) {
      f32x4 a = *(const f32x4*)(hp + q * 8);
      f32x4 b = *(const f32x4*)(hp + q * 8 + 4);
      s16x8 pk;
      pk[0] = (short)f2bf(a[0]); pk[1] = (short)f2bf(a[1]);
      pk[2] = (short)f2bf(a[2]); pk[3] = (short)f2bf(a[3]);
      pk[4] = (short)f2bf(b[0]); pk[5] = (short)f2bf(b[1]);
      pk[6] = (short)f2bf(b[2]); pk[7] = (short)f2bf(b[3]);
      unsigned byte = row_base + 256 + sct * 64 + q * 16;
      *(s16x8*)(lds + (byte ^ swz)) = pk;
    }
  }

  #pragma unroll 1
  for (int t = 0; t < S_; ++t) {
    unsigned short* hout = h_bf + ((t + 1) & 1) * (B_ * H2_);
    const unsigned short* hin = h_bf + (t & 1) * (B_ * H2_);
    const bool more = (t < S_ - 1);

    // ================= stream A compute =================
    __syncthreads();                       // SA1: Alds[0] ready
    f32x4 vxa0, vxa1;
    if (more) {
      const float* xp = x + ((size_t)b_stA * S_ + (t + 1)) * D_ + sct * 8;
      vxa0 = *(const f32x4*)xp;
      vxa1 = *(const f32x4*)(xp + 4);
    }
    {
      f32x4 acc0 = {0.f, 0.f, 0.f, 0.f};
      f32x4 acc1 = {0.f, 0.f, 0.f, 0.f};
      #pragma unroll
      for (int kk = 0; kk < 20; ++kk) {
        unsigned byte = (unsigned)(ar * (K_ * 2) + kk * 64 + ahi * 16);
        s16x8 af = *(const s16x8*)((const char*)Alds[0] + (byte ^ ((ar & 7) << 4)));
        acc0 = __builtin_amdgcn_mfma_f32_16x16x32_bf16(bfrag0[kk], af, acc0, 0, 0, 0);
        acc1 = __builtin_amdgcn_mfma_f32_16x16x32_bf16(bfrag1[kk], af, acc1, 0, 0, 0);
      }
      float i0 = sigm(acc0[0] + brg0[0]), f0 = sigm(acc0[1] + brg0[1]);
      float g0 = tanh_(acc0[2] + brg0[2]), o0 = sigm(acc0[3] + brg0[3]);
      cA[0] = f0 * cA[0] + i0 * g0;
      float hA0 = o0 * tanh_(cA[0]);  poolA[0] += hA0;
      float i1 = sigm(acc1[0] + brg1[0]), f1 = sigm(acc1[1] + brg1[1]);
      float g1 = tanh_(acc1[2] + brg1[2]), o1 = sigm(acc1[3] + brg1[3]);
      cA[1] = f1 * cA[1] + i1 * g1;
      float hA1 = o1 * tanh_(cA[1]);  poolA[1] += hA1;
      if (more) {
        unsigned packed = (unsigned)f2bf(hA0) | ((unsigned)f2bf(hA1) << 16);
        st_coh_u32((unsigned*)(hout + (size_t)b_ownA * H2_ + j0), packed);
      }
    }
    if (more) {
      s16x8 pk;                            // consume vxa (waits only those loads)
      pk[0] = (short)f2bf(vxa0[0]); pk[1] = (short)f2bf(vxa0[1]);
      pk[2] = (short)f2bf(vxa0[2]); pk[3] = (short)f2bf(vxa0[3]);
      pk[4] = (short)f2bf(vxa1[0]); pk[5] = (short)f2bf(vxa1[1]);
      pk[6] = (short)f2bf(vxa1[2]); pk[7] = (short)f2bf(vxa1[3]);
      vm_drain();                          // release: h_A stores at coherence point
      __syncthreads();                     // SA2
      if (tid == 0) st_coh_u32(fA + ng, (unsigned)(t + 1));
      *(s16x8*)((char*)Alds[0] + swz_x) = pk;   // x_A(t+1), off drain path
    }

    // ----- stage stream B: h_B(t) (prologue covered t=0) -----
    if (t > 0) {
      const unsigned tgt = (unsigned)t;
      const unsigned* fp = fB + (lane & 15);
      while (!__all(ld_coh_u32(fp) >= tgt))
        __builtin_amdgcn_s_sleep(1);
      const unsigned short* hrow = hin + (size_t)b_stB * H2_ + sct * 32;
      s16x8 hv0 = ld_cohx8(hrow);
      s16x8 hv1 = ld_cohx8(hrow + 8);
      s16x8 hv2 = ld_cohx8(hrow + 16);
      s16x8 hv3 = ld_cohx8(hrow + 24);
      vm_drain();
      unsigned byte = row_base + 256 + sct * 64;
      *(s16x8*)((char*)Alds[1] + ((byte     ) ^ swz)) = hv0;
      *(s16x8*)((char*)Alds[1] + ((byte + 16) ^ swz)) = hv1;
      *(s16x8*)((char*)Alds[1] + ((byte + 32) ^ swz)) = hv2;
      *(s16x8*)((char*)Alds[1] + ((byte + 48) ^ swz)) = hv3;
    }

    // ================= stream B compute =================
    __syncthreads();                       // SB1: Alds[1] ready
    f32x4 vxb0, vxb1;
    if (more) {
      const float* xp = x + ((size_t)b_stB * S_ + (t + 1)) * D_ + sct * 8;
      vxb0 = *(const f32x4*)xp;
      vxb1 = *(const f32x4*)(xp + 4);
    }
    {
      f32x4 acc0 = {0.f, 0.f, 0.f, 0.f};
      f32x4 acc1 = {0.f, 0.f, 0.f, 0.f};
      #pragma unroll
      for (int kk = 0; kk < 20; ++kk) {
        unsigned byte = (unsigned)(ar * (K_ * 2) + kk * 64 + ahi * 16);
        s16x8 af = *(const s16x8*)((const char*)Alds[1] + (byte ^ ((ar & 7) << 4)));
        acc0 = __builtin_amdgcn_mfma_f32_16x16x32_bf16(bfrag0[kk], af, acc0, 0, 0, 0);
        acc1 = __builtin_amdgcn_mfma_f32_16x16x32_bf16(bfrag1[kk], af, acc1, 0, 0, 0);
      }
      float i0 = sigm(acc0[0] + brg0[0]), f0 = sigm(acc0[1] + brg0[1]);
      float g0 = tanh_(acc0[2] + brg0[2]), o0 = sigm(acc0[3] + brg0[3]);
      cB[0] = f0 * cB[0] + i0 * g0;
      float hB0 = o0 * tanh_(cB[0]);  poolB[0] += hB0;
      float i1 = sigm(acc1[0] + brg1[0]), f1 = sigm(acc1[1] + brg1[1]);
      float g1 = tanh_(acc1[2] + brg1[2]), o1 = sigm(acc1[3] + brg1[3]);
      cB[1] = f1 * cB[1] + i1 * g1;
      float hB1 = o1 * tanh_(cB[1]);  poolB[1] += hB1;
      if (more) {
        unsigned packed = (unsigned)f2bf(hB0) | ((unsigned)f2bf(hB1) << 16);
        st_coh_u32((unsigned*)(hout + (size_t)b_ownB * H2_ + j0), packed);
      }
    }
    if (more) {
      s16x8 pk;
      pk[0] = (short)f2bf(vxb0[0]); pk[1] = (short)f2bf(vxb0[1]);
      pk[2] = (short)f2bf(vxb0[2]); pk[3] = (short)f2bf(vxb0[3]);
      pk[4] = (short)f2bf(vxb1[0]); pk[5] = (short)f2bf(vxb1[1]);
      pk[6] = (short)f2bf(vxb1[2]); pk[7] = (short)f2bf(vxb1[3]);
      vm_drain();                          // release: h_B stores
      __syncthreads();                     // SB2
      if (tid == 0) st_coh_u32(fB + ng, (unsigned)(t + 1));
      *(s16x8*)((char*)Alds[1] + swz_x) = pk;   // x_B(t+1)

      // ----- stage stream A: h_A(t+1) -----
      const unsigned tgt = (unsigned)(t + 1);
      const unsigned* fp = fA + (lane & 15);
      while (!__all(ld_coh_u32(fp) >= tgt))
        __builtin_amdgcn_s_sleep(1);
      const unsigned short* hrow = hout + (size_t)b_stA * H2_ + sct * 32;
      s16x8 hv0 = ld_cohx8(hrow);
      s16x8 hv1 = ld_cohx8(hrow + 8);
      s16x8 hv2 = ld_cohx8(hrow + 16);
      s16x8 hv3 = ld_cohx8(hrow + 24);
      vm_drain();
      unsigned byte = row_base + 256 + sct * 64;
      *(s16x8*)((char*)Alds[0] + ((byte     ) ^ swz)) = hv0;
      *(s16x8*)((char*)Alds[0] + ((byte + 16) ^ swz)) = hv1;
      *(s16x8*)((char*)Alds[0] + ((byte + 32) ^ swz)) = hv2;
      *(s16x8*)((char*)Alds[0] + ((byte + 48) ^ swz)) = hv3;
    }
  }

  *(f32x2*)(pooled + (size_t)b_ownA * H2_ + j0) = poolA;
  *(f32x2*)(pooled + (size_t)b_ownB * H2_ + j0) = poolB;
}

// ---------------- fused fc1(relu)+fc2 per batch row -------------------------
__global__ void fc_kernel(const float* __restrict__ pooled,
                          const float* __restrict__ fc1_w, const float* __restrict__ fc1_b,
                          const float* __restrict__ fc2_w, const float* __restrict__ fc2_b,
                          float* __restrict__ out) {
  const int b = blockIdx.x;
  const int tid = threadIdx.x;   // 256
  __shared__ float prow[H2_];
  __shared__ float dec[H2_];
  __shared__ float red[256];
  prow[tid]       = pooled[(size_t)b * H2_ + tid];
  prow[tid + 256] = pooled[(size_t)b * H2_ + tid + 256];
  __syncthreads();
  #pragma unroll
  for (int e = 0; e < 2; ++e) {
    const int o = tid + e * 256;
    const float* wrow = fc1_w + (size_t)o * H2_;
    float a = fc1_b[o];
    #pragma unroll 8
    for (int k = 0; k < H2_; ++k) a += prow[k] * wrow[k];
    dec[o] = fmaxf(a, 0.f);
  }
  __syncthreads();
  red[tid] = dec[tid] * fc2_w[tid] + dec[tid + 256] * fc2_w[tid + 256];
  __syncthreads();
  for (int s = 128; s > 0; s >>= 1) {
    if (tid < s) red[tid] += red[tid + s];
    __syncthreads();
  }
  if (tid == 0) out[b] = red[0] + fc2_b[0];
}

// ---------------- launch -----------------------------------------------------
extern "C" void kernel_launch(void* const* d_in, const int* in_sizes, int n_in,
                              void* d_out, int out_size, void* d_ws, size_t ws_size,
                              hipStream_t stream) {
  const float* x      = (const float*)d_in[0];
  const float* conv_w = (const float*)d_in[1];
  const float* conv_b = (const float*)d_in[2];
  const float* w_ih   = (const float*)d_in[3];
  const float* b_ih   = (const float*)d_in[4];
  const float* w_hh   = (const float*)d_in[5];
  const float* b_hh   = (const float*)d_in[6];
  const float* h0     = (const float*)d_in[7];
  const float* c0     = (const float*)d_in[8];
  const float* fc1_w  = (const float*)d_in[9];
  const float* fc1_b  = (const float*)d_in[10];
  const float* fc2_w  = (const float*)d_in[11];
  const float* fc2_b  = (const float*)d_in[12];
  float* out = (float*)d_out;

  char* ws = (char*)d_ws;
  // ws layout (bytes):
  //   Wc     [2048][640] bf16 : 0        .. 2621440
  //   bias   [2048]      f32  : 2621440  .. 2629632
  //   h_bf [2][256][512] bf16 : 2629632  .. 3153920
  //   pooled [256][512]  f32  : 3153920  .. 3678208
  //   flags  [2][8][16]  u32  : 3678208  .. 3679232
  unsigned short* Wc    = (unsigned short*)(ws);
  float* bias           = (float*)(ws + 2621440);
  unsigned short* h_bf  = (unsigned short*)(ws + 2629632);
  float* pooled         = (float*)(ws + 3153920);
  unsigned* flags       = (unsigned*)(ws + 3678208);

  prep_kernel<<<dim3(G4_), dim3(128), 0, stream>>>(conv_w, conv_b, w_ih, b_ih,
                                                   w_hh, b_hh, Wc, bias, flags);

  // Regular launch (no grid.sync in the kernel since round 7; 128 WGs on
  // 256 CUs are co-resident from the dispatcher without cooperative launch).
  lstm_kernel<<<dim3(128), dim3(256), 0, stream>>>(x, h0, c0, Wc, bias,
                                                   h_bf, pooled, flags);

  fc_kernel<<<dim3(B_), dim3(256), 0, stream>>>(pooled, fc1_w, fc1_b, fc2_w, fc2_b, out);
}